// Round 10
// baseline (165.375 us; speedup 1.0000x reference)
//
#include <hip/hip_runtime.h>
#include <math.h>

// Problem constants (fixed by setup_inputs)
#define B_    4
#define D_    96
#define H_    160
#define W_    160
#define HW_   (H_ * W_)
#define NVOX  (D_ * H_ * W_)
#define NBINS 50
#define NQR   28                    // 5 moments + 8 gab + 6 lbp + 9 glcm
#define CPB   256                   // chunks (blocks) per batch -> 1024 total = 4/CU
#define PART_F (B_ * NQR * CPB)     // 28672 floats of partials
#define HIST_U PART_F               // 4*50 uints global histogram after partials
#define WQ_F   (PART_F + 200)       // 23 uniform weight floats
#define LASTP ((D_ - 1) * HW_)

typedef float f2 __attribute__((ext_vector_type(2)));

// readfirstlane a float into an SGPR-resident uniform value
__device__ __forceinline__ float rfl(float v) {
    return __uint_as_float(__builtin_amdgcn_readfirstlane(__float_as_uint(v)));
}

// ---------------------------------------------------------------------------
// Pre-kernel: fit the z-separable + point-symmetric gabor model ONCE,
// pair-symmetrize coefficients (0/90 transpose pair, 45/135 flip pair),
// zero the global histogram.  Kept OUT of the main kernel: the fit's ~40
// live uniform temps inflate main's VGPR to 136-140 (R5-R7 evidence).
// LBP taps are exactly +1/-1 by construction -> hardcoded compare in main.
// ---------------------------------------------------------------------------
__global__ __launch_bounds__(64) void radiomics_weights(
    const float* __restrict__ gf, const float* __restrict__ lf,
    float* __restrict__ ws)
{
    const int lane = threadIdx.x;
    __shared__ float sCs[8][5], sR[8], sMO[8], sMC[8];
    if (lane < 8) {
        const int f = lane;
        float O9[9], C9[9];
        float mC = 0.f, mO = 0.f;
#pragma unroll
        for (int k = 0; k < 9; ++k) {
            O9[k] = gf[f * 27 + k];
            C9[k] = gf[f * 27 + 9 + k];
            mC += C9[k]; mO += O9[k];
        }
        mC *= (1.f / 9.f); mO *= (1.f / 9.f);
        float cov = 0.f, var = 0.f;
#pragma unroll
        for (int k = 0; k < 9; ++k) {
            float c = C9[k] - mC, o = O9[k] - mO;
            cov += c * o; var += c * c;
        }
        sR[f] = cov / var; sMO[f] = mO; sMC[f] = mC;
#pragma unroll
        for (int j = 0; j < 4; ++j) sCs[f][j] = 0.5f * (C9[j] + C9[8 - j]);
        sCs[f][4] = C9[4];
    }
    __syncthreads();
    if (lane == 0) {
        float* wq = ws + WQ_F;
        float gz0 = 0.f;
        for (int f = 0; f < 8; ++f) gz0 += sR[f];
        gz0 *= 0.125f;
        wq[0] = gz0;
        float df[8];
        for (int f = 0; f < 8; ++f) df[f] = sMO[f] - gz0 * sMC[f];
        for (int F = 0; F < 2; ++F) {
            const int f0 = 4 * F, f1 = 4 * F + 1, f2 = 4 * F + 2, f3 = 4 * F + 3;
            float* g = wq + 1 + 11 * F;
            g[0]  = 0.5f * (df[f0] + df[f2]);                       // dfA
            g[1]  = 0.5f * (sCs[f0][0] + sCs[f2][0]);               // s0  (P0)
            g[2]  = 0.5f * (sCs[f0][2] + sCs[f2][2]);               // s2  (P2)
            g[3]  = 0.5f * (sCs[f0][4] + sCs[f2][4]);               // s4  (ctr)
            g[4]  = 0.5f * (sCs[f0][1] + sCs[f2][3]);               // u   (P1 of 0deg)
            g[5]  = 0.5f * (sCs[f0][3] + sCs[f2][1]);               // w   (P3 of 0deg)
            g[6]  = 0.5f * (df[f1] + df[f3]);                       // dfB
            g[7]  = 0.25f * (sCs[f1][1] + sCs[f1][3]
                           + sCs[f3][1] + sCs[f3][3]);              // t   (Q)
            g[8]  = 0.5f * (sCs[f1][4] + sCs[f3][4]);               // e   (ctr)
            g[9]  = 0.5f * (sCs[f1][0] + sCs[f3][2]);               // a   (P0 of 45deg)
            g[10] = 0.5f * (sCs[f1][2] + sCs[f3][0]);               // b   (P2 of 45deg)
        }
    }
    unsigned int* gh = (unsigned int*)ws + HIST_U;
    for (int i = lane; i < B_ * NBINS; i += 64) gh[i] = 0u;
}

// load raw 3x4 window rows of plane at element offset zo into slot s
#define LOADP(s, zo) do {                                                   \
    _Pragma("unroll")                                                       \
    for (int r_ = 0; r_ < 3; ++r_) {                                        \
        Xw[s][r_][0] = xbb[(zo) + rowoff[r_] + xL];                         \
        f2 t_ = *(const f2*)(xbb + (zo) + rowoff[r_] + gx);                 \
        Xw[s][r_][1] = t_.x; Xw[s][r_][2] = t_.y;                           \
        Xw[s][r_][3] = xbb[(zo) + rowoff[r_] + xR];                         \
    }                                                                       \
} while (0)

// boundary handling + per-voxel 3x3 column sums for slot s.
// bzv (z-validity) is block-uniform {0,1}: zero path is a uniform branch.
#define FINISH(s, bzv) do {                                                 \
    if ((bzv) == 0.f) {                                                     \
        _Pragma("unroll")                                                   \
        for (int r_ = 0; r_ < 3; ++r_)                                      \
            _Pragma("unroll")                                               \
            for (int c_ = 0; c_ < 4; ++c_) Xw[s][r_][c_] = 0.f;             \
        S9[s][0] = S9[s][1] = 0.f;                                          \
    } else {                                                                \
        _Pragma("unroll")                                                   \
        for (int c_ = 0; c_ < 4; ++c_) {                                    \
            Xw[s][0][c_] *= bndRow0; Xw[s][2][c_] *= bndRow2;               \
        }                                                                   \
        _Pragma("unroll")                                                   \
        for (int r_ = 0; r_ < 3; ++r_) {                                    \
            Xw[s][r_][0] *= bndL; Xw[s][r_][3] *= bndR;                     \
        }                                                                   \
        float cs0_ = Xw[s][0][0] + Xw[s][1][0] + Xw[s][2][0];               \
        float cs1_ = Xw[s][0][1] + Xw[s][1][1] + Xw[s][2][1];               \
        float cs2_ = Xw[s][0][2] + Xw[s][1][2] + Xw[s][2][2];               \
        float cs3_ = Xw[s][0][3] + Xw[s][1][3] + Xw[s][2][3];               \
        S9[s][0] = cs0_ + cs1_ + cs2_;                                      \
        S9[s][1] = cs1_ + cs2_ + cs3_;                                      \
    }                                                                       \
} while (0)

// ---------------------------------------------------------------------------
// Main kernel: R2's proven direct-load register-window structure + R9's
// micro-opts (compare LBP, trunc binning, early/late reorder), with the
// R8/R9 SLOT-ROTATION BUG FIXED:
//   R9 used cs=j as center while the prologue fills center at slot 1 ->
//   plane z0+1 was overwritten before use and never processed (absmax
//   3.8e-6 -> 7.8e-3; passed only because all outputs are averages).
//   Correct mapping (matches prologue: slot0=z0-1, slot1=z0, slot2=z0+1):
//     c0 = j       (z-1)
//     cs = (j+1)&3 (center z)
//     c2 = (j+2)&3 (z+1, finished this iteration)
//     c3 = (j+3)&3 (receives z+2 prefetch)
// ---------------------------------------------------------------------------
__global__ __launch_bounds__(256) void radiomics_main(
    const float* __restrict__ x, const float* __restrict__ mask,
    float* __restrict__ ws)
{
    __shared__ unsigned int shist[4 * NBINS];
    __shared__ float xred[4][NQR];

    const int tid = threadIdx.x;
    const int tx = tid & 15, ty = tid >> 4;
    const int lane = tid & 63, wid = tid >> 6;

    for (int i = tid; i < 4 * NBINS; i += 256) shist[i] = 0u;

    // ---- uniform weights from pre-kernel (forced into SGPRs) ----
    const float* wq = ws + WQ_F;
    const float gz0 = rfl(wq[0]);
    float gco[22];
#pragma unroll
    for (int i = 0; i < 22; ++i) gco[i] = rfl(wq[1 + i]);

    // ---- decode chunk id -> (tile t, z-range [z0, z0+nz)) ----
    const int c = blockIdx.x;          // 0..255
    const int b = blockIdx.z;
    int t, z0, nz;
    if (c < 36) {                      // tiles 0..5: 6 chunks of 16
        t  = c / 6;
        const int ci = c - 6 * t;
        z0 = 16 * ci; nz = 16;
    } else {                           // tiles 6..49: 5 chunks {16,20,20,20,20}
        const int c2i = c - 36;
        const int ti = c2i / 5;
        const int ci = c2i - 5 * ti;
        t = 6 + ti;
        if (ci == 0) { z0 = 0; nz = 16; }
        else         { z0 = 20 * ci - 4; nz = 20; }
    }
    const int ngroups = nz >> 2;       // 4 or 5

    const int gx = (t % 5) * 32 + tx * 2;
    const int gy = (t / 5) * 16 + ty;

    const float* __restrict__ xbb = x    + (size_t)b * NVOX;
    const float* __restrict__ mbb = mask + (size_t)b * NVOX;

    const int gy0 = (gy > 0) ? gy - 1 : 0;
    const int gy2 = (gy + 1 < H_) ? gy + 1 : H_ - 1;
    const int rowoff[3] = { gy0 * W_, gy * W_, gy2 * W_ };
    const float bndRow0 = (gy > 0) ? 1.f : 0.f;
    const float bndRow2 = (gy + 1 < H_) ? 1.f : 0.f;
    const int xL = (gx > 0) ? gx - 1 : 0;
    const int xR = (gx + 2 < W_) ? gx + 2 : W_ - 1;
    const float bndL = (gx > 0) ? 1.f : 0.f;
    const float bndR = (gx + 2 < W_) ? 1.f : 0.f;
    const int moff  = gy * W_ + gx;
    const int myoff = gy2 * W_ + gx;
    const int mxoff = gy * W_ + xR;
    const float bym = bndRow2, bxm = bndR;

    float Xw[4][3][4];   // rotating z-slots, 3 y-rows, 4 x-cols
    float S9[4][2];      // per-slot per-voxel 3x3 sums
    float Mq[4][2];      // per-slot center mask pair
    float bzs[4];        // per-slot z-validity
    f2    myq[2];        // prefetched y+1 neighbor-mask pairs
    float mxq[2];        // prefetched x+2 neighbor mask
    float acc[NQR];
#pragma unroll
    for (int q = 0; q < NQR; ++q) acc[q] = 0.f;
    bzs[0] = bzs[1] = bzs[2] = 1.f;

    // init slots: 0 = z0-1 (finished), 1 = z0 (finished), 2 = z0+1 (raw)
    if (z0 == 0) {
#pragma unroll
        for (int r = 0; r < 3; ++r)
#pragma unroll
            for (int cc = 0; cc < 4; ++cc) Xw[0][r][cc] = 0.f;
        S9[0][0] = S9[0][1] = 0.f;
    } else {
        LOADP(0, (z0 - 1) * HW_);
        FINISH(0, 1.f);
    }
    LOADP(1, z0 * HW_);
    FINISH(1, 1.f);
    {
        f2 mm = *(const f2*)(mbb + z0 * HW_ + moff);
        Mq[1][0] = (mm.x > 0.5f) ? 1.f : 0.f;
        Mq[1][1] = (mm.y > 0.5f) ? 1.f : 0.f;
    }
    LOADP(2, (z0 + 1) * HW_);      // z0+1 <= 81 < 96 always valid
    {
        f2 mm = *(const f2*)(mbb + (z0 + 1) * HW_ + moff);
        Mq[2][0] = mm.x; Mq[2][1] = mm.y;    // raw
    }
    Mq[0][0] = Mq[0][1] = 0.f;
    myq[0] = *(const f2*)(mbb + z0 * HW_ + myoff);
    mxq[0] = mbb[z0 * HW_ + mxoff];

    int zc   = z0 * HW_;
    int zpre = (z0 + 2) * HW_;

#pragma unroll 1
    for (int g = 0; g < ngroups; ++g) {
#pragma unroll
        for (int j = 0; j < 4; ++j) {
            const int c0 = j & 3;              // slot of z-1
            const int cs = (j + 1) & 3;        // slot of center plane z
            const int c2 = (j + 2) & 3;        // slot of z+1 (finished below)
            const int c3 = (j + 3) & 3;        // slot receiving z+2 now
            const int cur = j & 1, nxt = cur ^ 1;

            // --- branchless prefetch: plane z+2 (clamped) + masks z+1 ---
            const int zpe = (zpre < NVOX) ? zpre : LASTP;     // uniform select
            bzs[c3] = (zpre < NVOX) ? 1.f : 0.f;
            LOADP(c3, zpe);
            {
                f2 mm = *(const f2*)(mbb + zpe + moff);
                Mq[c3][0] = mm.x; Mq[c3][1] = mm.y;           // raw
            }
            const int zn = (zc + HW_ < NVOX) ? zc + HW_ : LASTP;
            myq[nxt] = *(const f2*)(mbb + zn + myoff);
            mxq[nxt] = mbb[zn + mxoff];

            const f2 my2 = myq[cur];
            const float mxs = mxq[cur];

            // --- EARLY block: no z+1 (c2) dependence -> no load wait ---
#pragma unroll
            for (int q = 0; q < 2; ++q) {
                const float v  = Xw[cs][1][q + 1];
                const float mc = Mq[cs][q];

                // moments
                acc[0] += mc;
                float mv  = mc * v;  acc[1] += mv;
                float mv2 = mv * v;  acc[2] += mv2;
                float mv3 = mv2 * v; acc[3] += mv3;
                acc[4] += mv3 * v;

                // histogram: (v+1)*25 >= 0 inside guard -> trunc == floor
                if (mc > 0.5f && v >= -1.f && v <= 1.f) {
                    int bi = (int)((v + 1.f) * (NBINS * 0.5f));
                    bi = min(bi, NBINS - 1);
                    atomicAdd(&shist[(tid >> 6) * NBINS + bi], 1u);
                }

                // lbp taps 1..5 (z-1, y+1, y-1, x+1, x-1): exact +-1 weights
                acc[14] += (v > Xw[c0][1][q + 1]) ? mc : 0.f;
                acc[15] += (v > Xw[cs][2][q + 1]) ? mc : 0.f;
                acc[16] += (v > Xw[cs][0][q + 1]) ? mc : 0.f;
                acc[17] += (v > Xw[cs][1][q + 2]) ? mc : 0.f;
                acc[18] += (v > Xw[cs][1][q])     ? mc : 0.f;

                // glcm H axis
                {
                    float mr = (q == 0) ? my2.x : my2.y;
                    float mp = mc * (((mr > 0.5f) ? 1.f : 0.f) * bym);
                    float d = v - Xw[cs][2][q + 1], dd = d * d;
                    acc[20] += mp;
                    acc[23] = fmaf(mp, dd, acc[23]);
                    acc[26] = fmaf(mp, __builtin_amdgcn_rcpf(1.f + dd), acc[26]);
                }
                // glcm W axis
                {
                    float mnr = (q == 0) ? Mq[cs][1] : (((mxs > 0.5f) ? 1.f : 0.f) * bxm);
                    float mp = mc * mnr;
                    float d = v - Xw[cs][1][q + 2], dd = d * d;
                    acc[21] += mp;
                    acc[24] = fmaf(mp, dd, acc[24]);
                    acc[27] = fmaf(mp, __builtin_amdgcn_rcpf(1.f + dd), acc[27]);
                }
            }

            // --- finish plane z+1 (first wait on its loads lands here) ---
            FINISH(c2, bzs[c2]);
            Mq[c2][0] = (Mq[c2][0] * bzs[c2] > 0.5f) ? 1.f : 0.f;
            Mq[c2][1] = (Mq[c2][1] * bzs[c2] > 0.5f) ? 1.f : 0.f;

            // T = X(z) + gz0*(X(z-1)+X(z+1)), shared by both voxels/filters
            float T6[3][4];
#pragma unroll
            for (int r = 0; r < 3; ++r)
#pragma unroll
                for (int cc = 0; cc < 4; ++cc)
                    T6[r][cc] = fmaf(gz0, Xw[c0][r][cc] + Xw[c2][r][cc], Xw[cs][r][cc]);

            // --- LATE block: gabor + lbp z+1 tap + glcm D ---
#pragma unroll
            for (int q = 0; q < 2; ++q) {
                const float v  = Xw[cs][1][q + 1];
                const float mc = Mq[cs][q];

                // gabor: symmetry-paired dots on 7 shared partial sums
                float P0 = T6[0][q]     + T6[2][q + 2];
                float P1 = T6[0][q + 1] + T6[2][q + 1];
                float P2 = T6[0][q + 2] + T6[2][q];
                float P3 = T6[1][q]     + T6[1][q + 2];
                float ctrv = T6[1][q + 1];
                float S2 = S9[c0][q] + S9[c2][q];
                float Qv = P1 + P3;
#pragma unroll
                for (int F = 0; F < 2; ++F) {
                    const float dfA = gco[F*11+0], c0s = gco[F*11+1];
                    const float c2s = gco[F*11+2], c4s = gco[F*11+3];
                    const float cu  = gco[F*11+4], cw  = gco[F*11+5];
                    const float dfB = gco[F*11+6], ct  = gco[F*11+7];
                    const float ce  = gco[F*11+8], ca  = gco[F*11+9];
                    const float cb  = gco[F*11+10];
                    float E = dfA * S2;
                    E = fmaf(c0s, P0, E); E = fmaf(c2s, P2, E); E = fmaf(c4s, ctrv, E);
                    float r0   = fmaf(cu, P1, fmaf(cw, P3, E));
                    float r90  = fmaf(cw, P1, fmaf(cu, P3, E));
                    float G = fmaf(ct, Qv, dfB * S2);
                    G = fmaf(ce, ctrv, G);
                    float r45  = fmaf(ca, P0, fmaf(cb, P2, G));
                    float r135 = fmaf(cb, P0, fmaf(ca, P2, G));
                    acc[5 + 4*F + 0] = fmaf(fabsf(r0),   mc, acc[5 + 4*F + 0]);
                    acc[5 + 4*F + 1] = fmaf(fabsf(r45),  mc, acc[5 + 4*F + 1]);
                    acc[5 + 4*F + 2] = fmaf(fabsf(r90),  mc, acc[5 + 4*F + 2]);
                    acc[5 + 4*F + 3] = fmaf(fabsf(r135), mc, acc[5 + 4*F + 3]);
                }

                // lbp tap 0 (z+1 neighbor)
                acc[13] += (v > Xw[c2][1][q + 1]) ? mc : 0.f;

                // glcm D axis (Mq[c2] binarized incl. z-validity)
                {
                    float mp = mc * Mq[c2][q];
                    float d = v - Xw[c2][1][q + 1], dd = d * d;
                    acc[19] += mp;
                    acc[22] = fmaf(mp, dd, acc[22]);
                    acc[25] = fmaf(mp, __builtin_amdgcn_rcpf(1.f + dd), acc[25]);
                }
            }
            zc += HW_; zpre += HW_;
        }
    }

    // ---- block reduction + partial store (unique slot, no atomics) ----
#pragma unroll
    for (int q = 0; q < NQR; ++q) {
        float sm = acc[q];
#pragma unroll
        for (int o = 32; o > 0; o >>= 1)
            sm += __shfl_down(sm, o, 64);
        acc[q] = sm;
    }
    if (lane == 0) {
#pragma unroll
        for (int q = 0; q < NQR; ++q) xred[wid][q] = acc[q];
    }
    __syncthreads();

    if (tid < NQR) {
        float v = xred[0][tid] + xred[1][tid] + xred[2][tid] + xred[3][tid];
        ws[((size_t)b * NQR + tid) * CPB + c] = v;
    } else if (tid < NQR + NBINS) {
        int h = tid - NQR;
        unsigned int cnt = shist[h] + shist[NBINS + h]
                         + shist[2 * NBINS + h] + shist[3 * NBINS + h];
        unsigned int* ghist = (unsigned int*)ws + HIST_U;
        if (cnt) atomicAdd(&ghist[b * NBINS + h], cnt);
    }
}

// Fused tail: one block per batch (512 threads = 8 waves).
__global__ __launch_bounds__(512) void radiomics_tail(
    const float* __restrict__ ws, float* __restrict__ out)
{
    __shared__ double fin[NQR];
    __shared__ double hcnt[NBINS];
    __shared__ double entp[NBINS];
    __shared__ double sh_hsum;
    const int b = blockIdx.x, tid = threadIdx.x;
    const int wave = tid >> 6, lane = tid & 63;

    for (int q = wave; q < NQR; q += 8) {
        const float* p = ws + ((size_t)b * NQR + q) * CPB;
        double s = 0.0;
#pragma unroll
        for (int k = 0; k < 4; ++k)
            s += (double)p[lane + 64 * k];
#pragma unroll
        for (int o = 32; o > 0; o >>= 1)
            s += __shfl_down(s, o, 64);
        if (lane == 0) fin[q] = s;
    }
    if (tid < NBINS)
        hcnt[tid] = (double)(((const unsigned int*)ws)[HIST_U + b * NBINS + tid]);
    __syncthreads();

    if (tid == 0) {
        double h = 0.0;
        for (int k = 0; k < NBINS; ++k) h += hcnt[k];
        sh_hsum = h + 1e-8;
    }
    __syncthreads();

    if (tid < NBINS) {
        double p = hcnt[tid] / sh_hsum;
        entp[tid] = -p * log(p + 1e-8);
    }
    __syncthreads();

    if (tid == 0) {
        const double n  = fin[0];
        const double nn = fmax(n, 1.0);
        const double s1 = fin[1], s2 = fin[2], s3 = fin[3], s4 = fin[4];
        const double mu = s1 / nn;
        const double M2 = s2 - 2.0 * mu * s1 + mu * mu * n;
        const double M3 = s3 - 3.0 * mu * s2 + 3.0 * mu * mu * s1 - mu * mu * mu * n;
        const double M4 = s4 - 4.0 * mu * s3 + 6.0 * mu * mu * s2
                          - 4.0 * mu * mu * mu * s1 + mu * mu * mu * mu * n;
        const double var   = M2 / fmax(n - 1.0, 1.0);
        const double sigma = sqrt(var) + 1e-8;
        const double skew  = M3 / (sigma * sigma * sigma) / nn;
        const double kurt  = M4 / (sigma * sigma * sigma * sigma) / nn - 3.0;

        double ent = 0.0;
        for (int k = 0; k < NBINS; ++k) ent += entp[k];

        const double valid = (n >= 10.0) ? 1.0 : 0.0;
        float* ob = out + b * 25;
        ob[0] = (float)(mu * valid);
        ob[1] = (float)(sigma * valid);
        ob[2] = (float)(skew * valid);
        ob[3] = (float)(kurt * valid);
        ob[4] = (float)(ent * valid);

        const double lung = fmax(n, 1.0);
        for (int f = 0; f < 8; ++f) ob[5 + f]  = (float)(fin[5 + f] / lung);
        for (int f = 0; f < 6; ++f) ob[13 + f] = (float)(fin[13 + f] / lung);

        for (int ax = 0; ax < 3; ++ax) {
            double s  = fin[19 + ax];
            double ss = fmax(s, 1.0);
            double ok = (s >= 4.0) ? 1.0 : 0.0;
            ob[19 + 2 * ax]     = (float)(fin[22 + ax] / ss * ok);
            ob[19 + 2 * ax + 1] = (float)(fin[25 + ax] / ss * ok);
        }
    }
}

extern "C" void kernel_launch(void* const* d_in, const int* in_sizes, int n_in,
                              void* d_out, int out_size, void* d_ws, size_t ws_size,
                              hipStream_t stream)
{
    const float* x    = (const float*)d_in[0];
    const float* mask = (const float*)d_in[1];
    const float* gf   = (const float*)d_in[2];
    const float* lf   = (const float*)d_in[3];
    float* out = (float*)d_out;
    float* ws  = (float*)d_ws;   // ~116 KB used

    radiomics_weights<<<1, 64, 0, stream>>>(gf, lf, ws);
    // 256 chunks/batch x 4 batches = 1024 blocks = exactly 4/CU, balanced
    radiomics_main<<<dim3(256, 1, B_), 256, 0, stream>>>(x, mask, ws);
    radiomics_tail<<<B_, 512, 0, stream>>>(ws, out);
}

// Round 11
// 157.315 us; speedup vs baseline: 1.0512x; 1.0512x over previous
//
#include <hip/hip_runtime.h>
#include <math.h>

// Problem constants (fixed by setup_inputs)
#define B_    4
#define D_    96
#define H_    160
#define W_    160
#define HW_   (H_ * W_)
#define NVOX  (D_ * H_ * W_)
#define NBINS 50
#define NQR   28                    // 5 moments + 8 gab + 6 lbp + 9 glcm
#define CPB   256                   // chunks (blocks) per batch -> 1024 total = 4/CU
#define PART_F (B_ * NQR * CPB)     // 28672 floats of partials
#define HIST_U PART_F               // 4*50 uints global histogram after partials
#define WQ_F   (PART_F + 200)       // 23 uniform weight floats
#define LASTP ((D_ - 1) * HW_)

typedef float f2 __attribute__((ext_vector_type(2)));

// readfirstlane a float into an SGPR-resident uniform value
__device__ __forceinline__ float rfl(float v) {
    return __uint_as_float(__builtin_amdgcn_readfirstlane(__float_as_uint(v)));
}

// ---------------------------------------------------------------------------
// Pre-kernel: unchanged from R10 (fit gabor model once, zero global hist).
// ---------------------------------------------------------------------------
__global__ __launch_bounds__(64) void radiomics_weights(
    const float* __restrict__ gf, const float* __restrict__ lf,
    float* __restrict__ ws)
{
    const int lane = threadIdx.x;
    __shared__ float sCs[8][5], sR[8], sMO[8], sMC[8];
    if (lane < 8) {
        const int f = lane;
        float O9[9], C9[9];
        float mC = 0.f, mO = 0.f;
#pragma unroll
        for (int k = 0; k < 9; ++k) {
            O9[k] = gf[f * 27 + k];
            C9[k] = gf[f * 27 + 9 + k];
            mC += C9[k]; mO += O9[k];
        }
        mC *= (1.f / 9.f); mO *= (1.f / 9.f);
        float cov = 0.f, var = 0.f;
#pragma unroll
        for (int k = 0; k < 9; ++k) {
            float c = C9[k] - mC, o = O9[k] - mO;
            cov += c * o; var += c * c;
        }
        sR[f] = cov / var; sMO[f] = mO; sMC[f] = mC;
#pragma unroll
        for (int j = 0; j < 4; ++j) sCs[f][j] = 0.5f * (C9[j] + C9[8 - j]);
        sCs[f][4] = C9[4];
    }
    __syncthreads();
    if (lane == 0) {
        float* wq = ws + WQ_F;
        float gz0 = 0.f;
        for (int f = 0; f < 8; ++f) gz0 += sR[f];
        gz0 *= 0.125f;
        wq[0] = gz0;
        float df[8];
        for (int f = 0; f < 8; ++f) df[f] = sMO[f] - gz0 * sMC[f];
        for (int F = 0; F < 2; ++F) {
            const int f0 = 4 * F, f1 = 4 * F + 1, f2 = 4 * F + 2, f3 = 4 * F + 3;
            float* g = wq + 1 + 11 * F;
            g[0]  = 0.5f * (df[f0] + df[f2]);                       // dfA
            g[1]  = 0.5f * (sCs[f0][0] + sCs[f2][0]);               // s0  (P0)
            g[2]  = 0.5f * (sCs[f0][2] + sCs[f2][2]);               // s2  (P2)
            g[3]  = 0.5f * (sCs[f0][4] + sCs[f2][4]);               // s4  (ctr)
            g[4]  = 0.5f * (sCs[f0][1] + sCs[f2][3]);               // u   (P1 of 0deg)
            g[5]  = 0.5f * (sCs[f0][3] + sCs[f2][1]);               // w   (P3 of 0deg)
            g[6]  = 0.5f * (df[f1] + df[f3]);                       // dfB
            g[7]  = 0.25f * (sCs[f1][1] + sCs[f1][3]
                           + sCs[f3][1] + sCs[f3][3]);              // t   (Q)
            g[8]  = 0.5f * (sCs[f1][4] + sCs[f3][4]);               // e   (ctr)
            g[9]  = 0.5f * (sCs[f1][0] + sCs[f3][2]);               // a   (P0 of 45deg)
            g[10] = 0.5f * (sCs[f1][2] + sCs[f3][0]);               // b   (P2 of 45deg)
        }
    }
    unsigned int* gh = (unsigned int*)ws + HIST_U;
    for (int i = lane; i < B_ * NBINS; i += 64) gh[i] = 0u;
}

// Load own center row (into Xw[s][1]) + halo row (into hp[0..3]) for plane
// at element offset zo.  6 VMEM vs the old 9 (rows 0/2 come from shuffles).
#define LOADR(s, zo, hp) do {                                               \
    Xw[s][1][0] = xbb[(zo) + rowC + xL];                                    \
    f2 t_ = *(const f2*)(xbb + (zo) + rowC + gx);                           \
    Xw[s][1][1] = t_.x; Xw[s][1][2] = t_.y;                                 \
    Xw[s][1][3] = xbb[(zo) + rowC + xR];                                    \
    hp[0] = xbb[(zo) + rowH + xL];                                          \
    f2 h_ = *(const f2*)(xbb + (zo) + rowH + gx);                           \
    hp[1] = h_.x; hp[2] = h_.y;                                             \
    hp[3] = xbb[(zo) + rowH + xR];                                          \
} while (0)

// Boundary handling + window build + 3x3 column sums for slot s.
// Rows 0/2 are the y-neighbor lanes' (col-fixed) center rows via lane+-16
// shuffle; wave-edge rows (tyw==0 / tyw==3) take the halo regs instead.
// All boundary factors are {0,1} -> multiplies exact -> values bit-identical
// to the old 9-load FINISH.
#define FINISH(s, bzv, hp) do {                                             \
    if ((bzv) == 0.f) {                                                     \
        _Pragma("unroll")                                                   \
        for (int r_ = 0; r_ < 3; ++r_)                                      \
            _Pragma("unroll")                                               \
            for (int c_ = 0; c_ < 4; ++c_) Xw[s][r_][c_] = 0.f;             \
        S9[s][0] = S9[s][1] = 0.f;                                          \
    } else {                                                                \
        Xw[s][1][0] *= bndL; Xw[s][1][3] *= bndR;                           \
        const float hc_[4] = { hp[0] * bndL, hp[1], hp[2], hp[3] * bndR };  \
        _Pragma("unroll")                                                   \
        for (int c_ = 0; c_ < 4; ++c_) {                                    \
            float up_ = __shfl_up(Xw[s][1][c_], 16, 64);                    \
            float dn_ = __shfl_down(Xw[s][1][c_], 16, 64);                  \
            Xw[s][0][c_] = (isTop ? hc_[c_] : up_) * bndRow0;               \
            Xw[s][2][c_] = (isBot ? hc_[c_] : dn_) * bndRow2;               \
        }                                                                   \
        float cs0_ = Xw[s][0][0] + Xw[s][1][0] + Xw[s][2][0];               \
        float cs1_ = Xw[s][0][1] + Xw[s][1][1] + Xw[s][2][1];               \
        float cs2_ = Xw[s][0][2] + Xw[s][1][2] + Xw[s][2][2];               \
        float cs3_ = Xw[s][0][3] + Xw[s][1][3] + Xw[s][2][3];               \
        S9[s][0] = cs0_ + cs1_ + cs2_;                                      \
        S9[s][1] = cs1_ + cs2_ + cs3_;                                      \
    }                                                                       \
} while (0)

// ---------------------------------------------------------------------------
// Main kernel: R10's verified structure with the 9-load window replaced by
// 6 loads + lane+-16 shuffles.  Wave rows are tx-major (lane = tyw*16+tx),
// so a thread's y-neighbors are lane-16 / lane+16 IN THE SAME WAVE; only the
// wave-edge rows (tyw 0 and 3) need the halo load.  No LDS, no barriers,
// no async - the failure modes of R3/R4/R6/R7 are structurally absent.
// Halo regs ping-pong (hal[2][4], statically indexed in the unrolled loop).
// ---------------------------------------------------------------------------
__global__ __launch_bounds__(256) void radiomics_main(
    const float* __restrict__ x, const float* __restrict__ mask,
    float* __restrict__ ws)
{
    __shared__ unsigned int shist[4 * NBINS];
    __shared__ float xred[4][NQR];

    const int tid = threadIdx.x;
    const int tx = tid & 15, ty = tid >> 4;
    const int tyw = ty & 3;                  // row within wave (lane>>4)
    const int lane = tid & 63, wid = tid >> 6;
    const bool isTop = (tyw == 0);
    const bool isBot = (tyw == 3);

    for (int i = tid; i < 4 * NBINS; i += 256) shist[i] = 0u;

    // ---- uniform weights from pre-kernel (forced into SGPRs) ----
    const float* wq = ws + WQ_F;
    const float gz0 = rfl(wq[0]);
    float gco[22];
#pragma unroll
    for (int i = 0; i < 22; ++i) gco[i] = rfl(wq[1 + i]);

    // ---- decode chunk id -> (tile t, z-range [z0, z0+nz)) ----
    const int c = blockIdx.x;          // 0..255
    const int b = blockIdx.z;
    int t, z0, nz;
    if (c < 36) {                      // tiles 0..5: 6 chunks of 16
        t  = c / 6;
        const int ci = c - 6 * t;
        z0 = 16 * ci; nz = 16;
    } else {                           // tiles 6..49: 5 chunks {16,20,20,20,20}
        const int c2i = c - 36;
        const int ti = c2i / 5;
        const int ci = c2i - 5 * ti;
        t = 6 + ti;
        if (ci == 0) { z0 = 0; nz = 16; }
        else         { z0 = 20 * ci - 4; nz = 20; }
    }
    const int ngroups = nz >> 2;       // 4 or 5

    const int gx = (t % 5) * 32 + tx * 2;
    const int gy = (t / 5) * 16 + ty;

    const float* __restrict__ xbb = x    + (size_t)b * NVOX;
    const float* __restrict__ mbb = mask + (size_t)b * NVOX;

    const int gy0 = (gy > 0) ? gy - 1 : 0;
    const int gy2 = (gy + 1 < H_) ? gy + 1 : H_ - 1;
    const int rowC = gy * W_;
    const int rowH = (isBot ? gy2 : gy0) * W_;   // halo row: below for tyw3, above otherwise
    const float bndRow0 = (gy > 0) ? 1.f : 0.f;
    const float bndRow2 = (gy + 1 < H_) ? 1.f : 0.f;
    const int xL = (gx > 0) ? gx - 1 : 0;
    const int xR = (gx + 2 < W_) ? gx + 2 : W_ - 1;
    const float bndL = (gx > 0) ? 1.f : 0.f;
    const float bndR = (gx + 2 < W_) ? 1.f : 0.f;
    const int moff  = gy * W_ + gx;
    const int myoff = gy2 * W_ + gx;
    const int mxoff = gy * W_ + xR;
    const float bym = bndRow2, bxm = bndR;

    float Xw[4][3][4];   // rotating z-slots, 3 y-rows, 4 x-cols
    float S9[4][2];      // per-slot per-voxel 3x3 sums
    float Mq[4][2];      // per-slot center mask pair
    float bzs[4];        // per-slot z-validity
    float hal[2][4];     // ping-pong halo rows (issue hal[j&1], consume hal[(j+1)&1])
    f2    myq[2];        // prefetched y+1 neighbor-mask pairs
    float mxq[2];        // prefetched x+2 neighbor mask
    float acc[NQR];
#pragma unroll
    for (int q = 0; q < NQR; ++q) acc[q] = 0.f;
    bzs[0] = bzs[1] = bzs[2] = 1.f;

    // init slots: 0 = z0-1 (finished), 1 = z0 (finished), 2 = z0+1 (raw)
    if (z0 == 0) {
#pragma unroll
        for (int r = 0; r < 3; ++r)
#pragma unroll
            for (int cc = 0; cc < 4; ++cc) Xw[0][r][cc] = 0.f;
        S9[0][0] = S9[0][1] = 0.f;
    } else {
        LOADR(0, (z0 - 1) * HW_, hal[0]);
        FINISH(0, 1.f, hal[0]);
    }
    LOADR(1, z0 * HW_, hal[0]);
    FINISH(1, 1.f, hal[0]);
    {
        f2 mm = *(const f2*)(mbb + z0 * HW_ + moff);
        Mq[1][0] = (mm.x > 0.5f) ? 1.f : 0.f;
        Mq[1][1] = (mm.y > 0.5f) ? 1.f : 0.f;
    }
    LOADR(2, (z0 + 1) * HW_, hal[1]);  // z0+1 <= 81 < 96 always valid
    {
        f2 mm = *(const f2*)(mbb + (z0 + 1) * HW_ + moff);
        Mq[2][0] = mm.x; Mq[2][1] = mm.y;    // raw
    }
    Mq[0][0] = Mq[0][1] = 0.f;
    myq[0] = *(const f2*)(mbb + z0 * HW_ + myoff);
    mxq[0] = mbb[z0 * HW_ + mxoff];

    int zc   = z0 * HW_;
    int zpre = (z0 + 2) * HW_;

#pragma unroll 1
    for (int g = 0; g < ngroups; ++g) {
#pragma unroll
        for (int j = 0; j < 4; ++j) {
            const int c0 = j & 3;              // slot of z-1
            const int cs = (j + 1) & 3;        // slot of center plane z
            const int c2 = (j + 2) & 3;        // slot of z+1 (finished below)
            const int c3 = (j + 3) & 3;        // slot receiving z+2 now
            const int cur = j & 1, nxt = cur ^ 1;
            const int hIss = j & 1;            // halo buf issued this iter
            const int hCon = (j + 1) & 1;      // halo buf consumed this iter

            // --- branchless prefetch: plane z+2 (clamped) + masks z+1 ---
            const int zpe = (zpre < NVOX) ? zpre : LASTP;     // uniform select
            bzs[c3] = (zpre < NVOX) ? 1.f : 0.f;
            LOADR(c3, zpe, hal[hIss]);
            {
                f2 mm = *(const f2*)(mbb + zpe + moff);
                Mq[c3][0] = mm.x; Mq[c3][1] = mm.y;           // raw
            }
            const int zn = (zc + HW_ < NVOX) ? zc + HW_ : LASTP;
            myq[nxt] = *(const f2*)(mbb + zn + myoff);
            mxq[nxt] = mbb[zn + mxoff];

            const f2 my2 = myq[cur];
            const float mxs = mxq[cur];

            // --- EARLY block: no z+1 (c2) dependence -> no load wait ---
#pragma unroll
            for (int q = 0; q < 2; ++q) {
                const float v  = Xw[cs][1][q + 1];
                const float mc = Mq[cs][q];

                // moments
                acc[0] += mc;
                float mv  = mc * v;  acc[1] += mv;
                float mv2 = mv * v;  acc[2] += mv2;
                float mv3 = mv2 * v; acc[3] += mv3;
                acc[4] += mv3 * v;

                // histogram: (v+1)*25 >= 0 inside guard -> trunc == floor
                if (mc > 0.5f && v >= -1.f && v <= 1.f) {
                    int bi = (int)((v + 1.f) * (NBINS * 0.5f));
                    bi = min(bi, NBINS - 1);
                    atomicAdd(&shist[(tid >> 6) * NBINS + bi], 1u);
                }

                // lbp taps 1..5 (z-1, y+1, y-1, x+1, x-1): exact +-1 weights
                acc[14] += (v > Xw[c0][1][q + 1]) ? mc : 0.f;
                acc[15] += (v > Xw[cs][2][q + 1]) ? mc : 0.f;
                acc[16] += (v > Xw[cs][0][q + 1]) ? mc : 0.f;
                acc[17] += (v > Xw[cs][1][q + 2]) ? mc : 0.f;
                acc[18] += (v > Xw[cs][1][q])     ? mc : 0.f;

                // glcm H axis
                {
                    float mr = (q == 0) ? my2.x : my2.y;
                    float mp = mc * (((mr > 0.5f) ? 1.f : 0.f) * bym);
                    float d = v - Xw[cs][2][q + 1], dd = d * d;
                    acc[20] += mp;
                    acc[23] = fmaf(mp, dd, acc[23]);
                    acc[26] = fmaf(mp, __builtin_amdgcn_rcpf(1.f + dd), acc[26]);
                }
                // glcm W axis
                {
                    float mnr = (q == 0) ? Mq[cs][1] : (((mxs > 0.5f) ? 1.f : 0.f) * bxm);
                    float mp = mc * mnr;
                    float d = v - Xw[cs][1][q + 2], dd = d * d;
                    acc[21] += mp;
                    acc[24] = fmaf(mp, dd, acc[24]);
                    acc[27] = fmaf(mp, __builtin_amdgcn_rcpf(1.f + dd), acc[27]);
                }
            }

            // --- finish plane z+1 (first wait on its loads lands here) ---
            FINISH(c2, bzs[c2], hal[hCon]);
            Mq[c2][0] = (Mq[c2][0] * bzs[c2] > 0.5f) ? 1.f : 0.f;
            Mq[c2][1] = (Mq[c2][1] * bzs[c2] > 0.5f) ? 1.f : 0.f;

            // T = X(z) + gz0*(X(z-1)+X(z+1)), shared by both voxels/filters
            float T6[3][4];
#pragma unroll
            for (int r = 0; r < 3; ++r)
#pragma unroll
                for (int cc = 0; cc < 4; ++cc)
                    T6[r][cc] = fmaf(gz0, Xw[c0][r][cc] + Xw[c2][r][cc], Xw[cs][r][cc]);

            // --- LATE block: gabor + lbp z+1 tap + glcm D ---
#pragma unroll
            for (int q = 0; q < 2; ++q) {
                const float v  = Xw[cs][1][q + 1];
                const float mc = Mq[cs][q];

                // gabor: symmetry-paired dots on 7 shared partial sums
                float P0 = T6[0][q]     + T6[2][q + 2];
                float P1 = T6[0][q + 1] + T6[2][q + 1];
                float P2 = T6[0][q + 2] + T6[2][q];
                float P3 = T6[1][q]     + T6[1][q + 2];
                float ctrv = T6[1][q + 1];
                float S2 = S9[c0][q] + S9[c2][q];
                float Qv = P1 + P3;
#pragma unroll
                for (int F = 0; F < 2; ++F) {
                    const float dfA = gco[F*11+0], c0s = gco[F*11+1];
                    const float c2s = gco[F*11+2], c4s = gco[F*11+3];
                    const float cu  = gco[F*11+4], cw  = gco[F*11+5];
                    const float dfB = gco[F*11+6], ct  = gco[F*11+7];
                    const float ce  = gco[F*11+8], ca  = gco[F*11+9];
                    const float cb  = gco[F*11+10];
                    float E = dfA * S2;
                    E = fmaf(c0s, P0, E); E = fmaf(c2s, P2, E); E = fmaf(c4s, ctrv, E);
                    float r0   = fmaf(cu, P1, fmaf(cw, P3, E));
                    float r90  = fmaf(cw, P1, fmaf(cu, P3, E));
                    float G = fmaf(ct, Qv, dfB * S2);
                    G = fmaf(ce, ctrv, G);
                    float r45  = fmaf(ca, P0, fmaf(cb, P2, G));
                    float r135 = fmaf(cb, P0, fmaf(ca, P2, G));
                    acc[5 + 4*F + 0] = fmaf(fabsf(r0),   mc, acc[5 + 4*F + 0]);
                    acc[5 + 4*F + 1] = fmaf(fabsf(r45),  mc, acc[5 + 4*F + 1]);
                    acc[5 + 4*F + 2] = fmaf(fabsf(r90),  mc, acc[5 + 4*F + 2]);
                    acc[5 + 4*F + 3] = fmaf(fabsf(r135), mc, acc[5 + 4*F + 3]);
                }

                // lbp tap 0 (z+1 neighbor)
                acc[13] += (v > Xw[c2][1][q + 1]) ? mc : 0.f;

                // glcm D axis (Mq[c2] binarized incl. z-validity)
                {
                    float mp = mc * Mq[c2][q];
                    float d = v - Xw[c2][1][q + 1], dd = d * d;
                    acc[19] += mp;
                    acc[22] = fmaf(mp, dd, acc[22]);
                    acc[25] = fmaf(mp, __builtin_amdgcn_rcpf(1.f + dd), acc[25]);
                }
            }
            zc += HW_; zpre += HW_;
        }
    }

    // ---- block reduction + partial store (unique slot, no atomics) ----
#pragma unroll
    for (int q = 0; q < NQR; ++q) {
        float sm = acc[q];
#pragma unroll
        for (int o = 32; o > 0; o >>= 1)
            sm += __shfl_down(sm, o, 64);
        acc[q] = sm;
    }
    if (lane == 0) {
#pragma unroll
        for (int q = 0; q < NQR; ++q) xred[wid][q] = acc[q];
    }
    __syncthreads();

    if (tid < NQR) {
        float v = xred[0][tid] + xred[1][tid] + xred[2][tid] + xred[3][tid];
        ws[((size_t)b * NQR + tid) * CPB + c] = v;
    } else if (tid < NQR + NBINS) {
        int h = tid - NQR;
        unsigned int cnt = shist[h] + shist[NBINS + h]
                         + shist[2 * NBINS + h] + shist[3 * NBINS + h];
        unsigned int* ghist = (unsigned int*)ws + HIST_U;
        if (cnt) atomicAdd(&ghist[b * NBINS + h], cnt);
    }
}

// Fused tail: one block per batch (512 threads = 8 waves).  Unchanged.
__global__ __launch_bounds__(512) void radiomics_tail(
    const float* __restrict__ ws, float* __restrict__ out)
{
    __shared__ double fin[NQR];
    __shared__ double hcnt[NBINS];
    __shared__ double entp[NBINS];
    __shared__ double sh_hsum;
    const int b = blockIdx.x, tid = threadIdx.x;
    const int wave = tid >> 6, lane = tid & 63;

    for (int q = wave; q < NQR; q += 8) {
        const float* p = ws + ((size_t)b * NQR + q) * CPB;
        double s = 0.0;
#pragma unroll
        for (int k = 0; k < 4; ++k)
            s += (double)p[lane + 64 * k];
#pragma unroll
        for (int o = 32; o > 0; o >>= 1)
            s += __shfl_down(s, o, 64);
        if (lane == 0) fin[q] = s;
    }
    if (tid < NBINS)
        hcnt[tid] = (double)(((const unsigned int*)ws)[HIST_U + b * NBINS + tid]);
    __syncthreads();

    if (tid == 0) {
        double h = 0.0;
        for (int k = 0; k < NBINS; ++k) h += hcnt[k];
        sh_hsum = h + 1e-8;
    }
    __syncthreads();

    if (tid < NBINS) {
        double p = hcnt[tid] / sh_hsum;
        entp[tid] = -p * log(p + 1e-8);
    }
    __syncthreads();

    if (tid == 0) {
        const double n  = fin[0];
        const double nn = fmax(n, 1.0);
        const double s1 = fin[1], s2 = fin[2], s3 = fin[3], s4 = fin[4];
        const double mu = s1 / nn;
        const double M2 = s2 - 2.0 * mu * s1 + mu * mu * n;
        const double M3 = s3 - 3.0 * mu * s2 + 3.0 * mu * mu * s1 - mu * mu * mu * n;
        const double M4 = s4 - 4.0 * mu * s3 + 6.0 * mu * mu * s2
                          - 4.0 * mu * mu * mu * s1 + mu * mu * mu * mu * n;
        const double var   = M2 / fmax(n - 1.0, 1.0);
        const double sigma = sqrt(var) + 1e-8;
        const double skew  = M3 / (sigma * sigma * sigma) / nn;
        const double kurt  = M4 / (sigma * sigma * sigma * sigma) / nn - 3.0;

        double ent = 0.0;
        for (int k = 0; k < NBINS; ++k) ent += entp[k];

        const double valid = (n >= 10.0) ? 1.0 : 0.0;
        float* ob = out + b * 25;
        ob[0] = (float)(mu * valid);
        ob[1] = (float)(sigma * valid);
        ob[2] = (float)(skew * valid);
        ob[3] = (float)(kurt * valid);
        ob[4] = (float)(ent * valid);

        const double lung = fmax(n, 1.0);
        for (int f = 0; f < 8; ++f) ob[5 + f]  = (float)(fin[5 + f] / lung);
        for (int f = 0; f < 6; ++f) ob[13 + f] = (float)(fin[13 + f] / lung);

        for (int ax = 0; ax < 3; ++ax) {
            double s  = fin[19 + ax];
            double ss = fmax(s, 1.0);
            double ok = (s >= 4.0) ? 1.0 : 0.0;
            ob[19 + 2 * ax]     = (float)(fin[22 + ax] / ss * ok);
            ob[19 + 2 * ax + 1] = (float)(fin[25 + ax] / ss * ok);
        }
    }
}

extern "C" void kernel_launch(void* const* d_in, const int* in_sizes, int n_in,
                              void* d_out, int out_size, void* d_ws, size_t ws_size,
                              hipStream_t stream)
{
    const float* x    = (const float*)d_in[0];
    const float* mask = (const float*)d_in[1];
    const float* gf   = (const float*)d_in[2];
    const float* lf   = (const float*)d_in[3];
    float* out = (float*)d_out;
    float* ws  = (float*)d_ws;   // ~116 KB used

    radiomics_weights<<<1, 64, 0, stream>>>(gf, lf, ws);
    // 256 chunks/batch x 4 batches = 1024 blocks = exactly 4/CU, balanced
    radiomics_main<<<dim3(256, 1, B_), 256, 0, stream>>>(x, mask, ws);
    radiomics_tail<<<B_, 512, 0, stream>>>(ws, out);
}